// Round 12
// baseline (136.017 us; speedup 1.0000x reference)
//
#include <hip/hip_runtime.h>

constexpr int NN = 100000;
constexpr int CH = 128;
constexpr int NE = 625000;
constexpr int NSCAN = (NN + 1023) / 1024;          // 98 scan blocks
constexpr int GEMM_BLOCKS = (NN + 127) / 128;      // 782 (128 rows/block, 32/wave)
constexpr int HIST_BLOCKS = NE / 8 / 256 + 1;      // 306 (8 edges/thread)
constexpr int ZERO_BLOCKS = (NN + 255) / 256;      // 391
constexpr int WCONV_BLOCKS = 16;                   // 16384 elems / 1024

typedef __bf16 bf16x8 __attribute__((ext_vector_type(8)));
typedef __bf16 bf16x4 __attribute__((ext_vector_type(4)));
typedef float  f32x4  __attribute__((ext_vector_type(4)));

__device__ __forceinline__ float bflo(uint u) { return __uint_as_float(u << 16); }
__device__ __forceinline__ float bfhi(uint u) { return __uint_as_float(u & 0xffff0000u); }

// ---- fused: zero cnt + convert W to bf16 (once per launch) ----
__global__ __launch_bounds__(256) void zero_wconv_kernel(
    int* __restrict__ cnt, const float* __restrict__ W, __bf16* __restrict__ Wb)
{
    if (blockIdx.x < ZERO_BLOCKS) {
        int i = blockIdx.x * 256 + threadIdx.x;
        if (i < NN) cnt[i] = 0;
        return;
    }
    int i = (blockIdx.x - ZERO_BLOCKS) * 256 + threadIdx.x;   // float4 group
    float4 v = reinterpret_cast<const float4*>(W)[i];
    bf16x4 h = {(__bf16)v.x, (__bf16)v.y, (__bf16)v.z, (__bf16)v.w};
    reinterpret_cast<bf16x4*>(Wb)[i] = h;
}

// ---- fused: MFMA GEMM (blocks < GEMM_BLOCKS) + edge histogram w/ rank ----
// GEMM: W fully register-resident per wave: wfrag[8][4] = 128 VGPR, loaded
// once from L2-resident bf16 Wb (no cvt). t-loop is pure MFMA + stores.
// 32 rows/wave (2 n-tiles), launch_bounds(256,2) -> VGPR cap 256.
// Hist: rank[e] = atomicAdd(&cnt[dst[e]], 1), 8 edges/thread (ILP-batched).
__global__ __launch_bounds__(256, 2) void gemm_hist_kernel(
    const float* __restrict__ x, const __bf16* __restrict__ Wb,
    const float* __restrict__ b, __bf16* __restrict__ xt,
    const int* __restrict__ ei, int* __restrict__ cnt, int* __restrict__ rank)
{
    if (blockIdx.x >= GEMM_BLOCKS) {
        const int t = (blockIdx.x - GEMM_BLOCKS) * 256 + threadIdx.x;
        if (t * 8 < NE) {
            int4 d0 = reinterpret_cast<const int4*>(ei + NE)[t * 2];
            int4 d1 = reinterpret_cast<const int4*>(ei + NE)[t * 2 + 1];
            int r0 = atomicAdd(&cnt[d0.x], 1);
            int r1 = atomicAdd(&cnt[d0.y], 1);
            int r2 = atomicAdd(&cnt[d0.z], 1);
            int r3 = atomicAdd(&cnt[d0.w], 1);
            int r4 = atomicAdd(&cnt[d1.x], 1);
            int r5 = atomicAdd(&cnt[d1.y], 1);
            int r6 = atomicAdd(&cnt[d1.z], 1);
            int r7 = atomicAdd(&cnt[d1.w], 1);
            reinterpret_cast<int4*>(rank)[t * 2]     = make_int4(r0, r1, r2, r3);
            reinterpret_cast<int4*>(rank)[t * 2 + 1] = make_int4(r4, r5, r6, r7);
        }
        return;
    }

    const int tid  = threadIdx.x;
    const int lane = tid & 63;
    const int lm = lane & 15;          // tile-local row (n) / W channel (m)
    const int lk = lane >> 4;          // k-group / channel-quad selector
    const int row0 = blockIdx.x * 128 + (tid >> 6) * 32;

    const int rowA = row0 + lm;        // n-tile 0
    const int rowB = row0 + 16 + lm;   // n-tile 1
    const int ra = rowA < NN ? rowA : NN - 1;
    const int rb = rowB < NN ? rowB : NN - 1;
    const float* xrowA = x + (size_t)ra * CH;
    const float* xrowB = x + (size_t)rb * CH;

    // x fragments first (HBM latency): 2 tiles x 4 k-steps, 16 dwordx4 loads
    bf16x8 bfragA[4], bfragB[4];
    #pragma unroll
    for (int ks = 0; ks < 4; ++ks) {
        const float4* pa = reinterpret_cast<const float4*>(xrowA + ks * 32 + lk * 8);
        const float4* pb = reinterpret_cast<const float4*>(xrowB + ks * 32 + lk * 8);
        float4 u = pa[0], v = pa[1];
        bfragA[ks][0] = (__bf16)u.x; bfragA[ks][1] = (__bf16)u.y;
        bfragA[ks][2] = (__bf16)u.z; bfragA[ks][3] = (__bf16)u.w;
        bfragA[ks][4] = (__bf16)v.x; bfragA[ks][5] = (__bf16)v.y;
        bfragA[ks][6] = (__bf16)v.z; bfragA[ks][7] = (__bf16)v.w;
        u = pb[0]; v = pb[1];
        bfragB[ks][0] = (__bf16)u.x; bfragB[ks][1] = (__bf16)u.y;
        bfragB[ks][2] = (__bf16)u.z; bfragB[ks][3] = (__bf16)u.w;
        bfragB[ks][4] = (__bf16)v.x; bfragB[ks][5] = (__bf16)v.y;
        bfragB[ks][6] = (__bf16)v.z; bfragB[ks][7] = (__bf16)v.w;
    }

    // Full W slice into registers: 32 dwordx4 from L2, no cvt.
    bf16x8 wfrag[8][4];
    #pragma unroll
    for (int t = 0; t < 8; ++t)
        #pragma unroll
        for (int ks = 0; ks < 4; ++ks)
            wfrag[t][ks] = *reinterpret_cast<const bf16x8*>(
                Wb + (t * 16 + lm) * 128 + ks * 32 + lk * 8);

    const float4* B4 = reinterpret_cast<const float4*>(b);

    #pragma unroll
    for (int t = 0; t < 8; ++t) {
        float4 bv = B4[t * 4 + lk];
        f32x4 acc0 = {bv.x, bv.y, bv.z, bv.w};
        f32x4 acc1 = acc0;
        #pragma unroll
        for (int ks = 0; ks < 4; ++ks) {
            acc0 = __builtin_amdgcn_mfma_f32_16x16x32_bf16(wfrag[t][ks], bfragA[ks], acc0, 0, 0, 0);
            acc1 = __builtin_amdgcn_mfma_f32_16x16x32_bf16(wfrag[t][ks], bfragB[ks], acc1, 0, 0, 0);
        }
        // D: col(lane&15) = node row, row((lane>>4)*4+reg) = channel
        const int c0 = t * 16 + lk * 4;
        if (rowA < NN) {
            bf16x4 hv = {(__bf16)acc0[0], (__bf16)acc0[1], (__bf16)acc0[2], (__bf16)acc0[3]};
            *reinterpret_cast<bf16x4*>(&xt[(size_t)rowA * CH + c0]) = hv;
        }
        if (rowB < NN) {
            bf16x4 hv = {(__bf16)acc1[0], (__bf16)acc1[1], (__bf16)acc1[2], (__bf16)acc1[3]};
            *reinterpret_cast<bf16x4*>(&xt[(size_t)rowB * CH + c0]) = hv;
        }
    }
}

__global__ __launch_bounds__(256) void scan_local_kernel(
    const int* __restrict__ cnt, int* __restrict__ loff,
    int* __restrict__ blocksums)
{
    __shared__ int tsum[256];
    const int t = threadIdx.x;
    const int base = blockIdx.x * 1024 + t * 4;
    int v[4];
    #pragma unroll
    for (int k = 0; k < 4; ++k) {
        int i = base + k;
        v[k] = (i < NN) ? cnt[i] : 0;
    }
    const int s = v[0] + v[1] + v[2] + v[3];
    tsum[t] = s;
    __syncthreads();
    for (int off = 1; off < 256; off <<= 1) {
        int u = (t >= off) ? tsum[t - off] : 0;
        __syncthreads();
        tsum[t] += u;
        __syncthreads();
    }
    int run = tsum[t] - s;
    #pragma unroll
    for (int k = 0; k < 4; ++k) {
        int i = base + k;
        if (i < NN) loff[i] = run;
        run += v[k];
    }
    if (t == 255) blocksums[blockIdx.x] = tsum[255];
}

__global__ __launch_bounds__(128) void scan_blocks_kernel(int* __restrict__ blocksums)
{
    __shared__ int sm[128];
    const int t = threadIdx.x;
    int v = (t < NSCAN) ? blocksums[t] : 0;
    sm[t] = v;
    __syncthreads();
    for (int off = 1; off < 128; off <<= 1) {
        int u = (t >= off) ? sm[t - off] : 0;
        __syncthreads();
        sm[t] += u;
        __syncthreads();
    }
    if (t < NSCAN) blocksums[t] = sm[t] - v;
}

__global__ __launch_bounds__(256) void scan_add_kernel(
    const int* __restrict__ loff, const int* __restrict__ blocksums,
    int* __restrict__ offs)
{
    int i = blockIdx.x * 256 + threadIdx.x;
    if (i > NN) return;
    if (i == NN) { offs[NN] = NE; return; }
    offs[i] = loff[i] + blocksums[i >> 10];
}

// Atomic-free placement: srcs[offs[dst] + rank[e]] = src, 4 edges/thread.
__global__ __launch_bounds__(256) void place_kernel(
    const int* __restrict__ ei, const int* __restrict__ rank,
    const int* __restrict__ offs, int* __restrict__ srcs)
{
    const int t = blockIdx.x * 256 + threadIdx.x;
    if (t * 4 >= NE) return;
    int4 s = reinterpret_cast<const int4*>(ei)[t];
    int4 d = reinterpret_cast<const int4*>(ei + NE)[t];
    int4 r = reinterpret_cast<const int4*>(rank)[t];
    int p0 = offs[d.x] + r.x;
    int p1 = offs[d.y] + r.y;
    int p2 = offs[d.z] + r.z;
    int p3 = offs[d.w] + r.w;
    srcs[p0] = s.x;
    srcs[p1] = s.y;
    srcs[p2] = s.z;
    srcs[p3] = s.w;
}

// ---- gather-reduce: one wave per dst node; 2 edges/step (half-wave split) --
__global__ __launch_bounds__(256) void gather_kernel(
    const uint2* __restrict__ xtu2,        // xt rows: [NN][32] uint2 (4 bf16)
    const int* __restrict__ offs, const int* __restrict__ srcs,
    float* __restrict__ out)
{
    const int wid = (blockIdx.x * 256 + threadIdx.x) >> 6;
    if (wid >= NN) return;
    const int lane = threadIdx.x & 63;
    const int half = lane >> 5;
    const int l32  = lane & 31;

    uint2 own = xtu2[(size_t)wid * 32 + l32];   // residual, consumed at end

    float4 acc = {0.f, 0.f, 0.f, 0.f};
    int beg = offs[wid];
    const int end = offs[wid + 1];

    while (beg < end) {
        const int n = min(end - beg, 64);
        const int myidx = (lane < n) ? srcs[beg + lane] : 0;
        int k = 0;
        for (; k + 3 < n; k += 4) {              // 4 edges/iter, 2 loads/lane
            int s0 = __shfl(myidx, k + half);
            int s1 = __shfl(myidx, k + 2 + half);
            uint2 h0 = xtu2[(size_t)s0 * 32 + l32];
            uint2 h1 = xtu2[(size_t)s1 * 32 + l32];
            acc.x += bflo(h0.x); acc.y += bfhi(h0.x);
            acc.z += bflo(h0.y); acc.w += bfhi(h0.y);
            acc.x += bflo(h1.x); acc.y += bfhi(h1.x);
            acc.z += bflo(h1.y); acc.w += bfhi(h1.y);
        }
        for (; k < n; k += 2) {                  // masked tail, 2 edges/iter
            const int kk = k + half;
            int s0 = __shfl(myidx, kk < n ? kk : 0);
            uint2 h0 = xtu2[(size_t)s0 * 32 + l32];
            if (kk < n) {
                acc.x += bflo(h0.x); acc.y += bfhi(h0.x);
                acc.z += bflo(h0.y); acc.w += bfhi(h0.y);
            }
        }
        beg += n;
    }

    acc.x += __shfl_xor(acc.x, 32);
    acc.y += __shfl_xor(acc.y, 32);
    acc.z += __shfl_xor(acc.z, 32);
    acc.w += __shfl_xor(acc.w, 32);

    if (half == 0) {
        acc.x += bflo(own.x); acc.y += bfhi(own.x);
        acc.z += bflo(own.y); acc.w += bfhi(own.y);
        reinterpret_cast<float4*>(out)[(size_t)wid * 32 + l32] = acc;
    }
}

extern "C" void kernel_launch(void* const* d_in, const int* in_sizes, int n_in,
                              void* d_out, int out_size, void* d_ws, size_t ws_size,
                              hipStream_t stream) {
    const float* x  = (const float*)d_in[0];
    const int*   ei = (const int*)d_in[1];   // [2][NE] int32
    const float* W  = (const float*)d_in[2];
    const float* b  = (const float*)d_in[3];
    float* out = (float*)d_out;

    __bf16* xt   = (__bf16*)d_ws;                     // NN*CH bf16 = 25.6 MB
    int*   cnt   = (int*)(xt + (size_t)NN * CH);      // NN
    int*   loff  = cnt + NN;                          // NN
    int*   offs  = loff + NN;                         // NN+1
    int*   bsums = offs + NN + 1;                     // 131
    int*   rank  = bsums + 131;                       // NE
    int*   srcs  = rank + NE;                         // NE
    __bf16* Wb   = (__bf16*)(srcs + NE);              // 16384 bf16 (16B-aligned)

    zero_wconv_kernel<<<ZERO_BLOCKS + WCONV_BLOCKS, 256, 0, stream>>>(cnt, W, Wb);
    gemm_hist_kernel<<<GEMM_BLOCKS + HIST_BLOCKS, 256, 0, stream>>>(
        x, Wb, b, xt, ei, cnt, rank);
    scan_local_kernel<<<NSCAN, 256, 0, stream>>>(cnt, loff, bsums);
    scan_blocks_kernel<<<1, 128, 0, stream>>>(bsums);
    scan_add_kernel<<<(NN + 1 + 255) / 256, 256, 0, stream>>>(loff, bsums, offs);
    place_kernel<<<(NE / 4 + 255) / 256, 256, 0, stream>>>(ei, rank, offs, srcs);
    gather_kernel<<<(NN * 64 + 255) / 256, 256, 0, stream>>>(
        (const uint2*)xt, offs, srcs, out);
}

// Round 13
// 104.676 us; speedup vs baseline: 1.2994x; 1.2994x over previous
//
#include <hip/hip_runtime.h>

constexpr int NN = 100000;
constexpr int CH = 128;
constexpr int NE = 625000;
constexpr int NSCAN = (NN + 1023) / 1024;          // 98 scan blocks
constexpr int GEMM_BLOCKS = (NN + 63) / 64;        // 1563 (64 rows/block, 16/wave)
constexpr int HIST_BLOCKS = (NE / 8 + 255) / 256;  // 306 (8 edges/thread)
constexpr int ZERO_BLOCKS = (NN + 255) / 256;      // 391
constexpr int WCONV_BLOCKS = 16;                   // 16384 elems / 1024

typedef __bf16 bf16x8 __attribute__((ext_vector_type(8)));
typedef __bf16 bf16x4 __attribute__((ext_vector_type(4)));
typedef float  f32x4  __attribute__((ext_vector_type(4)));

__device__ __forceinline__ float bflo(uint u) { return __uint_as_float(u << 16); }
__device__ __forceinline__ float bfhi(uint u) { return __uint_as_float(u & 0xffff0000u); }

// ---- fused: zero cnt + convert W to bf16 SWIZZLED (once per launch) ----
// Wb[ch*128 + (k ^ ((ch&7)<<3))] = bf16(W[ch][k])  -> GEMM stages it linearly
// and ds_reads with the same XOR (bank-conflict-free, swizzle baked in global).
__global__ __launch_bounds__(256) void zero_wconv_kernel(
    int* __restrict__ cnt, const float* __restrict__ W, __bf16* __restrict__ Wb)
{
    if (blockIdx.x < ZERO_BLOCKS) {
        int i = blockIdx.x * 256 + threadIdx.x;
        if (i < NN) cnt[i] = 0;
        return;
    }
    int i = (blockIdx.x - ZERO_BLOCKS) * 256 + threadIdx.x;   // float4 group
    int ch = i >> 5;
    int k0 = (i & 31) * 4;
    float4 v = reinterpret_cast<const float4*>(W)[i];
    bf16x4 h = {(__bf16)v.x, (__bf16)v.y, (__bf16)v.z, (__bf16)v.w};
    // k0 is a multiple of 4; XOR touches bits 3..5 only -> stays 4-aligned
    *reinterpret_cast<bf16x4*>(&Wb[ch * 128 + (k0 ^ ((ch & 7) << 3))]) = h;
}

// ---- fused: edge histogram w/ rank (blocks < HIST_BLOCKS) + MFMA GEMM ----
// Hist FIRST in the grid so atomic streams overlap the GEMM from the start.
// GEMM: W staged to LDS via linear 16B copy of pre-swizzled Wb (8 loads +
// 8 ds_write_b128 per thread, no cvt). 16 rows/wave, 64 rows/block ->
// 1563 blocks = ~24 waves/CU. t-loop: 4 ds_read_b128 + 4 MFMA + 1 store.
__global__ __launch_bounds__(256) void gemm_hist_kernel(
    const float* __restrict__ x, const __bf16* __restrict__ Wb,
    const float* __restrict__ b, __bf16* __restrict__ xt,
    const int* __restrict__ ei, int* __restrict__ cnt, int* __restrict__ rank)
{
    if (blockIdx.x < HIST_BLOCKS) {
        const int t = blockIdx.x * 256 + threadIdx.x;
        if (t * 8 < NE) {
            int4 d0 = reinterpret_cast<const int4*>(ei + NE)[t * 2];
            int4 d1 = reinterpret_cast<const int4*>(ei + NE)[t * 2 + 1];
            int r0 = atomicAdd(&cnt[d0.x], 1);
            int r1 = atomicAdd(&cnt[d0.y], 1);
            int r2 = atomicAdd(&cnt[d0.z], 1);
            int r3 = atomicAdd(&cnt[d0.w], 1);
            int r4 = atomicAdd(&cnt[d1.x], 1);
            int r5 = atomicAdd(&cnt[d1.y], 1);
            int r6 = atomicAdd(&cnt[d1.z], 1);
            int r7 = atomicAdd(&cnt[d1.w], 1);
            reinterpret_cast<int4*>(rank)[t * 2]     = make_int4(r0, r1, r2, r3);
            reinterpret_cast<int4*>(rank)[t * 2 + 1] = make_int4(r4, r5, r6, r7);
        }
        return;
    }

    __shared__ __bf16 wlds[128 * 128];     // 32 KB, same layout as Wb (swizzled)
    const int tid = threadIdx.x;

    // Linear staging: 2048 granules of 16B, 256 threads -> 8 iterations.
    const bf16x8* Wb8 = reinterpret_cast<const bf16x8*>(Wb);
    #pragma unroll
    for (int it = 0; it < 8; ++it)
        reinterpret_cast<bf16x8*>(wlds)[it * 256 + tid] = Wb8[it * 256 + tid];

    const int lane = tid & 63;
    const int lm = lane & 15;              // x row (n) / W channel (m) in tile
    const int lk = lane >> 4;              // k-group / channel-quad selector
    const int row = (blockIdx.x - HIST_BLOCKS) * 64 + (tid >> 6) * 16 + lm;
    const int rc  = row < NN ? row : NN - 1;

    // x fragment: 4 k-steps, 8 bf16 each (8 independent dwordx4 loads)
    const float* xrow = x + (size_t)rc * CH;
    bf16x8 bfrag[4];
    #pragma unroll
    for (int ks = 0; ks < 4; ++ks) {
        const float4* p = reinterpret_cast<const float4*>(xrow + ks * 32 + lk * 8);
        float4 u = p[0], v = p[1];
        bfrag[ks][0] = (__bf16)u.x; bfrag[ks][1] = (__bf16)u.y;
        bfrag[ks][2] = (__bf16)u.z; bfrag[ks][3] = (__bf16)u.w;
        bfrag[ks][4] = (__bf16)v.x; bfrag[ks][5] = (__bf16)v.y;
        bfrag[ks][6] = (__bf16)v.z; bfrag[ks][7] = (__bf16)v.w;
    }

    __syncthreads();

    const float4* B4 = reinterpret_cast<const float4*>(b);
    const int swz = (lm & 7) << 3;         // ch&7 == lm&7 for every t (t*16 ≡ 0 mod 8)

    #pragma unroll
    for (int t = 0; t < 8; ++t) {
        const int ch = t * 16 + lm;        // A-fragment m index (W channel)
        float4 bv = B4[t * 4 + lk];
        f32x4 acc = {bv.x, bv.y, bv.z, bv.w};
        #pragma unroll
        for (int ks = 0; ks < 4; ++ks) {
            bf16x8 afrag = *reinterpret_cast<const bf16x8*>(
                &wlds[ch * 128 + ((ks * 32 + lk * 8) ^ swz)]);
            acc = __builtin_amdgcn_mfma_f32_16x16x32_bf16(afrag, bfrag[ks], acc, 0, 0, 0);
        }
        // D: col(lane&15) = node row, row((lane>>4)*4+reg) = channel
        if (row < NN) {
            const int c0 = t * 16 + lk * 4;
            bf16x4 hv = {(__bf16)acc[0], (__bf16)acc[1], (__bf16)acc[2], (__bf16)acc[3]};
            *reinterpret_cast<bf16x4*>(&xt[(size_t)row * CH + c0]) = hv;
        }
    }
}

__global__ __launch_bounds__(256) void scan_local_kernel(
    const int* __restrict__ cnt, int* __restrict__ loff,
    int* __restrict__ blocksums)
{
    __shared__ int tsum[256];
    const int t = threadIdx.x;
    const int base = blockIdx.x * 1024 + t * 4;
    int v[4];
    #pragma unroll
    for (int k = 0; k < 4; ++k) {
        int i = base + k;
        v[k] = (i < NN) ? cnt[i] : 0;
    }
    const int s = v[0] + v[1] + v[2] + v[3];
    tsum[t] = s;
    __syncthreads();
    for (int off = 1; off < 256; off <<= 1) {
        int u = (t >= off) ? tsum[t - off] : 0;
        __syncthreads();
        tsum[t] += u;
        __syncthreads();
    }
    int run = tsum[t] - s;
    #pragma unroll
    for (int k = 0; k < 4; ++k) {
        int i = base + k;
        if (i < NN) loff[i] = run;
        run += v[k];
    }
    if (t == 255) blocksums[blockIdx.x] = tsum[255];
}

__global__ __launch_bounds__(128) void scan_blocks_kernel(int* __restrict__ blocksums)
{
    __shared__ int sm[128];
    const int t = threadIdx.x;
    int v = (t < NSCAN) ? blocksums[t] : 0;
    sm[t] = v;
    __syncthreads();
    for (int off = 1; off < 128; off <<= 1) {
        int u = (t >= off) ? sm[t - off] : 0;
        __syncthreads();
        sm[t] += u;
        __syncthreads();
    }
    if (t < NSCAN) blocksums[t] = sm[t] - v;
}

__global__ __launch_bounds__(256) void scan_add_kernel(
    const int* __restrict__ loff, const int* __restrict__ blocksums,
    int* __restrict__ offs)
{
    int i = blockIdx.x * 256 + threadIdx.x;
    if (i > NN) return;
    if (i == NN) { offs[NN] = NE; return; }
    offs[i] = loff[i] + blocksums[i >> 10];
}

// Atomic-free placement: srcs[offs[dst] + rank[e]] = src, 4 edges/thread.
__global__ __launch_bounds__(256) void place_kernel(
    const int* __restrict__ ei, const int* __restrict__ rank,
    const int* __restrict__ offs, int* __restrict__ srcs)
{
    const int t = blockIdx.x * 256 + threadIdx.x;
    if (t * 4 >= NE) return;
    int4 s = reinterpret_cast<const int4*>(ei)[t];
    int4 d = reinterpret_cast<const int4*>(ei + NE)[t];
    int4 r = reinterpret_cast<const int4*>(rank)[t];
    int p0 = offs[d.x] + r.x;
    int p1 = offs[d.y] + r.y;
    int p2 = offs[d.z] + r.z;
    int p3 = offs[d.w] + r.w;
    srcs[p0] = s.x;
    srcs[p1] = s.y;
    srcs[p2] = s.z;
    srcs[p3] = s.w;
}

// ---- gather-reduce: one wave per dst node; 2 edges/step (half-wave split) --
__global__ __launch_bounds__(256) void gather_kernel(
    const uint2* __restrict__ xtu2,        // xt rows: [NN][32] uint2 (4 bf16)
    const int* __restrict__ offs, const int* __restrict__ srcs,
    float* __restrict__ out)
{
    const int wid = (blockIdx.x * 256 + threadIdx.x) >> 6;
    if (wid >= NN) return;
    const int lane = threadIdx.x & 63;
    const int half = lane >> 5;
    const int l32  = lane & 31;

    uint2 own = xtu2[(size_t)wid * 32 + l32];   // residual, consumed at end

    float4 acc = {0.f, 0.f, 0.f, 0.f};
    int beg = offs[wid];
    const int end = offs[wid + 1];

    while (beg < end) {
        const int n = min(end - beg, 64);
        const int myidx = (lane < n) ? srcs[beg + lane] : 0;
        int k = 0;
        for (; k + 3 < n; k += 4) {              // 4 edges/iter, 2 loads/lane
            int s0 = __shfl(myidx, k + half);
            int s1 = __shfl(myidx, k + 2 + half);
            uint2 h0 = xtu2[(size_t)s0 * 32 + l32];
            uint2 h1 = xtu2[(size_t)s1 * 32 + l32];
            acc.x += bflo(h0.x); acc.y += bfhi(h0.x);
            acc.z += bflo(h0.y); acc.w += bfhi(h0.y);
            acc.x += bflo(h1.x); acc.y += bfhi(h1.x);
            acc.z += bflo(h1.y); acc.w += bfhi(h1.y);
        }
        for (; k < n; k += 2) {                  // masked tail, 2 edges/iter
            const int kk = k + half;
            int s0 = __shfl(myidx, kk < n ? kk : 0);
            uint2 h0 = xtu2[(size_t)s0 * 32 + l32];
            if (kk < n) {
                acc.x += bflo(h0.x); acc.y += bfhi(h0.x);
                acc.z += bflo(h0.y); acc.w += bfhi(h0.y);
            }
        }
        beg += n;
    }

    acc.x += __shfl_xor(acc.x, 32);
    acc.y += __shfl_xor(acc.y, 32);
    acc.z += __shfl_xor(acc.z, 32);
    acc.w += __shfl_xor(acc.w, 32);

    if (half == 0) {
        acc.x += bflo(own.x); acc.y += bfhi(own.x);
        acc.z += bflo(own.y); acc.w += bfhi(own.y);
        reinterpret_cast<float4*>(out)[(size_t)wid * 32 + l32] = acc;
    }
}

extern "C" void kernel_launch(void* const* d_in, const int* in_sizes, int n_in,
                              void* d_out, int out_size, void* d_ws, size_t ws_size,
                              hipStream_t stream) {
    const float* x  = (const float*)d_in[0];
    const int*   ei = (const int*)d_in[1];   // [2][NE] int32
    const float* W  = (const float*)d_in[2];
    const float* b  = (const float*)d_in[3];
    float* out = (float*)d_out;

    __bf16* xt   = (__bf16*)d_ws;                     // NN*CH bf16 = 25.6 MB
    int*   cnt   = (int*)(xt + (size_t)NN * CH);      // NN
    int*   loff  = cnt + NN;                          // NN
    int*   offs  = loff + NN;                         // NN+1
    int*   bsums = offs + NN + 1;                     // 131
    int*   rank  = bsums + 131;                       // NE
    int*   srcs  = rank + NE;                         // NE
    __bf16* Wb   = (__bf16*)(srcs + NE);              // 16384 bf16 (16B-aligned)

    zero_wconv_kernel<<<ZERO_BLOCKS + WCONV_BLOCKS, 256, 0, stream>>>(cnt, W, Wb);
    gemm_hist_kernel<<<HIST_BLOCKS + GEMM_BLOCKS, 256, 0, stream>>>(
        x, Wb, b, xt, ei, cnt, rank);
    scan_local_kernel<<<NSCAN, 256, 0, stream>>>(cnt, loff, bsums);
    scan_blocks_kernel<<<1, 128, 0, stream>>>(bsums);
    scan_add_kernel<<<(NN + 1 + 255) / 256, 256, 0, stream>>>(loff, bsums, offs);
    place_kernel<<<(NE / 4 + 255) / 256, 256, 0, stream>>>(ei, rank, offs, srcs);
    gather_kernel<<<(NN * 64 + 255) / 256, 256, 0, stream>>>(
        (const uint2*)xt, offs, srcs, out);
}

// Round 14
// 85.287 us; speedup vs baseline: 1.5948x; 1.2273x over previous
//
#include <hip/hip_runtime.h>

constexpr int NN = 100000;
constexpr int CH = 128;
constexpr int NE = 625000;
constexpr int GEMM_BLOCKS = (NN + 63) / 64;        // 1563 (64 rows/block, 16/wave)
constexpr int BUCKET_BLOCKS = 256;                 // phase-1 bucketing blocks
constexpr int EDGES_PER_BLOCK = (NE + BUCKET_BLOCKS - 1) / BUCKET_BLOCKS;  // 2442
constexpr int NB = 196;                            // ceil(NN/512) coarse buckets
constexpr int CAP = 4096;                          // slots/bucket (max ~3390)
constexpr int WCONV_BLOCKS = 16;                   // 16384 elems / 1024

typedef __bf16 bf16x8 __attribute__((ext_vector_type(8)));
typedef __bf16 bf16x4 __attribute__((ext_vector_type(4)));
typedef float  f32x4  __attribute__((ext_vector_type(4)));

__device__ __forceinline__ float bflo(uint u) { return __uint_as_float(u << 16); }
__device__ __forceinline__ float bfhi(uint u) { return __uint_as_float(u & 0xffff0000u); }

// ---- prep: init bucket cursors + convert W to bf16 swizzled ----
__global__ __launch_bounds__(256) void prep_kernel(
    int* __restrict__ gcursor, const float* __restrict__ W, __bf16* __restrict__ Wb)
{
    if (blockIdx.x == 0) {
        gcursor[threadIdx.x] = threadIdx.x * CAP;
        return;
    }
    int i = (blockIdx.x - 1) * 256 + threadIdx.x;   // float4 group, 4096 total
    int ch = i >> 5;
    int k0 = (i & 31) * 4;
    float4 v = reinterpret_cast<const float4*>(W)[i];
    bf16x4 h = {(__bf16)v.x, (__bf16)v.y, (__bf16)v.z, (__bf16)v.w};
    *reinterpret_cast<bf16x4*>(&Wb[ch * 128 + (k0 ^ ((ch & 7) << 3))]) = h;
}

// ---- fused: coarse bucketing (blocks < BUCKET_BLOCKS) + MFMA GEMM ----
// Bucket: per-edge work is LDS atomics only; global atomics are one
// range-reservation per (block, nonempty bin) — <=50K total (vs 625K).
// GEMM: identical to r13 (pre-swizzled Wb staged linearly to LDS).
__global__ __launch_bounds__(256) void gemm_bucket_kernel(
    const float* __restrict__ x, const __bf16* __restrict__ Wb,
    const float* __restrict__ b, __bf16* __restrict__ xt,
    const int* __restrict__ ei, int* __restrict__ gcursor, int2* __restrict__ pairs)
{
    __shared__ __bf16 wlds[128 * 128];     // GEMM staging (32 KB)
    __shared__ int lhist[256];
    __shared__ int lbase[256];
    const int tid = threadIdx.x;

    if (blockIdx.x < BUCKET_BLOCKS) {
        const int e0 = blockIdx.x * EDGES_PER_BLOCK;
        const int myN = min(NE - e0, EDGES_PER_BLOCK);
        lhist[tid] = 0;
        __syncthreads();
        for (int i = tid; i < myN; i += 256) {
            int dst = ei[NE + e0 + i];
            atomicAdd(&lhist[dst >> 9], 1);
        }
        __syncthreads();
        {
            int c = lhist[tid];
            if (c) lbase[tid] = atomicAdd(&gcursor[tid], c);
            lhist[tid] = 0;
        }
        __syncthreads();
        for (int i = tid; i < myN; i += 256) {
            int src = ei[e0 + i];
            int dst = ei[NE + e0 + i];
            int bin = dst >> 9;
            int r = atomicAdd(&lhist[bin], 1);
            pairs[lbase[bin] + r] = make_int2(src, dst);
        }
        return;
    }

    // Linear staging of pre-swizzled Wb: 2048 granules of 16B.
    const bf16x8* Wb8 = reinterpret_cast<const bf16x8*>(Wb);
    #pragma unroll
    for (int it = 0; it < 8; ++it)
        reinterpret_cast<bf16x8*>(wlds)[it * 256 + tid] = Wb8[it * 256 + tid];

    const int lane = tid & 63;
    const int lm = lane & 15;              // x row (n) / W channel (m) in tile
    const int lk = lane >> 4;              // k-group / channel-quad selector
    const int row = (blockIdx.x - BUCKET_BLOCKS) * 64 + (tid >> 6) * 16 + lm;
    const int rc  = row < NN ? row : NN - 1;

    const float* xrow = x + (size_t)rc * CH;
    bf16x8 bfrag[4];
    #pragma unroll
    for (int ks = 0; ks < 4; ++ks) {
        const float4* p = reinterpret_cast<const float4*>(xrow + ks * 32 + lk * 8);
        float4 u = p[0], v = p[1];
        bfrag[ks][0] = (__bf16)u.x; bfrag[ks][1] = (__bf16)u.y;
        bfrag[ks][2] = (__bf16)u.z; bfrag[ks][3] = (__bf16)u.w;
        bfrag[ks][4] = (__bf16)v.x; bfrag[ks][5] = (__bf16)v.y;
        bfrag[ks][6] = (__bf16)v.z; bfrag[ks][7] = (__bf16)v.w;
    }

    __syncthreads();

    const float4* B4 = reinterpret_cast<const float4*>(b);
    const int swz = (lm & 7) << 3;

    #pragma unroll
    for (int t = 0; t < 8; ++t) {
        const int ch = t * 16 + lm;
        float4 bv = B4[t * 4 + lk];
        f32x4 acc = {bv.x, bv.y, bv.z, bv.w};
        #pragma unroll
        for (int ks = 0; ks < 4; ++ks) {
            bf16x8 afrag = *reinterpret_cast<const bf16x8*>(
                &wlds[ch * 128 + ((ks * 32 + lk * 8) ^ swz)]);
            acc = __builtin_amdgcn_mfma_f32_16x16x32_bf16(afrag, bfrag[ks], acc, 0, 0, 0);
        }
        if (row < NN) {
            const int c0 = t * 16 + lk * 4;
            bf16x4 hv = {(__bf16)acc[0], (__bf16)acc[1], (__bf16)acc[2], (__bf16)acc[3]};
            *reinterpret_cast<bf16x4*>(&xt[(size_t)row * CH + c0]) = hv;
        }
    }
}

// ---- phase 2: per-bucket LDS counting sort -> dense srcs + offs ----
// One block per bucket (512 dst values). All per-edge atomics are LDS.
__global__ __launch_bounds__(256) void place2_kernel(
    const int* __restrict__ gcursor, const int2* __restrict__ pairs,
    int* __restrict__ srcs, int* __restrict__ offs)
{
    __shared__ int cntb[256];      // bucket counts -> scan -> dense bases
    __shared__ int cnt512[512];
    __shared__ int pref[512];      // prefix, then reused as cursor
    __shared__ int dense_base;
    const int tid = threadIdx.x;
    const int bkt = blockIdx.x;

    // redundant per-block scan of all bucket counts (256 values)
    int c = gcursor[tid] - tid * CAP;     // 0 for unused bins
    cntb[tid] = c;
    __syncthreads();
    for (int off = 1; off < 256; off <<= 1) {
        int u = (tid >= off) ? cntb[tid - off] : 0;
        __syncthreads();
        cntb[tid] += u;
        __syncthreads();
    }
    if (tid == bkt) dense_base = cntb[tid] - c;        // exclusive prefix
    if (bkt == 0 && tid == 255) offs[NN] = cntb[255];  // == NE
    __syncthreads();

    const int n = gcursor[bkt] - bkt * CAP;
    const int2* P = pairs + (size_t)bkt * CAP;

    cnt512[tid] = 0; cnt512[tid + 256] = 0;
    __syncthreads();
    for (int i = tid; i < n; i += 256)
        atomicAdd(&cnt512[P[i].y & 511], 1);
    __syncthreads();

    // exclusive scan of 512 bins (2 bins/thread)
    int c0 = cnt512[2 * tid], c1 = cnt512[2 * tid + 1];
    int ps = c0 + c1;
    cntb[tid] = ps;
    __syncthreads();
    for (int off = 1; off < 256; off <<= 1) {
        int u = (tid >= off) ? cntb[tid - off] : 0;
        __syncthreads();
        cntb[tid] += u;
        __syncthreads();
    }
    int ex = cntb[tid] - ps;
    pref[2 * tid] = ex;
    pref[2 * tid + 1] = ex + c0;

    // write offs for this bucket's dsts
    {
        int d0 = bkt * 512 + 2 * tid;
        if (d0 < NN)     offs[d0]     = dense_base + ex;
        if (d0 + 1 < NN) offs[d0 + 1] = dense_base + ex + c0;
    }
    __syncthreads();

    // place: LDS cursor gives unique slot per edge within its dst
    for (int i = tid; i < n; i += 256) {
        int2 p = P[i];
        int pos = atomicAdd(&pref[p.y & 511], 1);
        srcs[dense_base + pos] = p.x;
    }
}

// ---- gather-reduce: one wave per dst node; 2 edges/step (half-wave split) --
__global__ __launch_bounds__(256) void gather_kernel(
    const uint2* __restrict__ xtu2,        // xt rows: [NN][32] uint2 (4 bf16)
    const int* __restrict__ offs, const int* __restrict__ srcs,
    float* __restrict__ out)
{
    const int wid = (blockIdx.x * 256 + threadIdx.x) >> 6;
    if (wid >= NN) return;
    const int lane = threadIdx.x & 63;
    const int half = lane >> 5;
    const int l32  = lane & 31;

    uint2 own = xtu2[(size_t)wid * 32 + l32];   // residual, consumed at end

    float4 acc = {0.f, 0.f, 0.f, 0.f};
    int beg = offs[wid];
    const int end = offs[wid + 1];

    while (beg < end) {
        const int n = min(end - beg, 64);
        const int myidx = (lane < n) ? srcs[beg + lane] : 0;
        int k = 0;
        for (; k + 3 < n; k += 4) {              // 4 edges/iter, 2 loads/lane
            int s0 = __shfl(myidx, k + half);
            int s1 = __shfl(myidx, k + 2 + half);
            uint2 h0 = xtu2[(size_t)s0 * 32 + l32];
            uint2 h1 = xtu2[(size_t)s1 * 32 + l32];
            acc.x += bflo(h0.x); acc.y += bfhi(h0.x);
            acc.z += bflo(h0.y); acc.w += bfhi(h0.y);
            acc.x += bflo(h1.x); acc.y += bfhi(h1.x);
            acc.z += bflo(h1.y); acc.w += bfhi(h1.y);
        }
        for (; k < n; k += 2) {                  // masked tail, 2 edges/iter
            const int kk = k + half;
            int s0 = __shfl(myidx, kk < n ? kk : 0);
            uint2 h0 = xtu2[(size_t)s0 * 32 + l32];
            if (kk < n) {
                acc.x += bflo(h0.x); acc.y += bfhi(h0.x);
                acc.z += bflo(h0.y); acc.w += bfhi(h0.y);
            }
        }
        beg += n;
    }

    acc.x += __shfl_xor(acc.x, 32);
    acc.y += __shfl_xor(acc.y, 32);
    acc.z += __shfl_xor(acc.z, 32);
    acc.w += __shfl_xor(acc.w, 32);

    if (half == 0) {
        acc.x += bflo(own.x); acc.y += bfhi(own.x);
        acc.z += bflo(own.y); acc.w += bfhi(own.y);
        reinterpret_cast<float4*>(out)[(size_t)wid * 32 + l32] = acc;
    }
}

extern "C" void kernel_launch(void* const* d_in, const int* in_sizes, int n_in,
                              void* d_out, int out_size, void* d_ws, size_t ws_size,
                              hipStream_t stream) {
    const float* x  = (const float*)d_in[0];
    const int*   ei = (const int*)d_in[1];   // [2][NE] int32
    const float* W  = (const float*)d_in[2];
    const float* b  = (const float*)d_in[3];
    float* out = (float*)d_out;

    __bf16* xt     = (__bf16*)d_ws;                       // 25.6 MB
    int2*   pairs  = (int2*)(xt + (size_t)NN * CH);       // 256*CAP*8B = 8 MB
    int*    srcs   = (int*)(pairs + (size_t)256 * CAP);   // NE = 2.5 MB
    int*    offs   = srcs + NE;                           // NN+1
    int*    gcur   = offs + NN + 1;                       // 256
    __bf16* Wb     = (__bf16*)(gcur + 256);               // 32 KB (4B-aligned ok)

    prep_kernel<<<1 + WCONV_BLOCKS, 256, 0, stream>>>(gcur, W, Wb);
    gemm_bucket_kernel<<<BUCKET_BLOCKS + GEMM_BLOCKS, 256, 0, stream>>>(
        x, Wb, b, xt, ei, gcur, pairs);
    place2_kernel<<<NB, 256, 0, stream>>>(gcur, pairs, srcs, offs);
    gather_kernel<<<(NN * 64 + 255) / 256, 256, 0, stream>>>(
        (const uint2*)xt, offs, srcs, out);
}